// Round 10
// baseline (140.792 us; speedup 1.0000x reference)
//
#include <hip/hip_runtime.h>
#include <hip/hip_bf16.h>

#define B_   2048
#define N_   1024
#define BETA 0.001f
#define VAR_MIN 1e-7f

#define PTS   64
#define NSTG  (N_ / PTS)       // 16 stages
#define RF    128              // floats per LDS row (64 pts x 2ch); rows contiguous
#define NBUF  3                // 3-deep pipeline: prefetch 2 stages ahead

typedef __attribute__((ext_vector_type(8))) short  bf16x8;
typedef __attribute__((ext_vector_type(4))) float  f32x4;

__device__ __forceinline__ unsigned short f2bf_u(float x) {
    __hip_bfloat16 h = __float2bfloat16(x);   // RNE
    return __builtin_bit_cast(unsigned short, h);
}
// hot-path softplus: 2 HW transcendentals. x<-16: 1+e^x -> 1 -> sp=0 -> VAR_MIN
// clamp, matching the reference's max(var, VAR_MIN).
__device__ __forceinline__ float softplus_cheap(float x) {
    float sp = __logf(1.f + __expf(x));
    return x > 15.f ? x : sp;
}
__device__ __forceinline__ float rcp_fast(float x) {
    return __builtin_amdgcn_rcpf(x);
}
__device__ __forceinline__ float softplus_ref(float x) {
    return x > 20.f ? x : log1pf(expf(x));
}

// pi(k): contraction-position permutation letting the previous layer's
// C-layout registers feed the next MFMA's B positions with zero cross-lane
// movement (verified absmax 0.0 in R4/R5/R6/R8/R9).
__device__ __forceinline__ int kperm(int k) {
    return 4 * (k >> 3) + (k & 3) + 16 * ((k >> 2) & 1);
}

extern "C" __global__ void hib_prep(const float* __restrict__ W1,
                                    const float* __restrict__ W2,
                                    const float* __restrict__ Wmu,
                                    const float* __restrict__ Wv,
                                    unsigned short* __restrict__ wf)
{
    const int l = threadIdx.x;         // 0..63
    const int r = l & 15, kb = l >> 4;
#pragma unroll
    for (int j = 0; j < 8; j++) {
        const int k1 = kb * 8 + j;
        const int kp = kperm(k1);
        wf[(0 * 64 + l) * 8 + j] = f2bf_u(W1[k1 * 32 + r]);
        wf[(1 * 64 + l) * 8 + j] = f2bf_u(W1[k1 * 32 + 16 + r]);
        wf[(2 * 64 + l) * 8 + j] = f2bf_u(W2[kp * 32 + r]);
        wf[(3 * 64 + l) * 8 + j] = f2bf_u(W2[kp * 32 + 16 + r]);
        wf[(4 * 64 + l) * 8 + j] = f2bf_u(r < 8 ? Wmu[kp * 8 + r]
                                                : Wv[kp * 8 + (r - 8)]);
    }
}

__device__ __forceinline__ bf16x8 pack_relu(f32x4 a, f32x4 b) {
    bf16x8 o;
    o[0] = (short)f2bf_u(fmaxf(a[0], 0.f));
    o[1] = (short)f2bf_u(fmaxf(a[1], 0.f));
    o[2] = (short)f2bf_u(fmaxf(a[2], 0.f));
    o[3] = (short)f2bf_u(fmaxf(a[3], 0.f));
    o[4] = (short)f2bf_u(fmaxf(b[0], 0.f));
    o[5] = (short)f2bf_u(fmaxf(b[1], 0.f));
    o[6] = (short)f2bf_u(fmaxf(b[2], 0.f));
    o[7] = (short)f2bf_u(fmaxf(b[3], 0.f));
    return o;
}

__device__ __forceinline__ void red16(f32x4& v) {
#pragma unroll
    for (int off = 8; off; off >>= 1) {
        v[0] += __shfl_down(v[0], off);
        v[1] += __shfl_down(v[1], off);
        v[2] += __shfl_down(v[2], off);
        v[3] += __shfl_down(v[3], off);
    }
}

// one stage's global->LDS for this wave: 4 x 1KB instrs, each covering 2 rows
__device__ __forceinline__ void stage_issue(const float* __restrict__ bbase,
                                            float* __restrict__ ldsbuf,
                                            int st, int wid, int l)
{
    const int sub = l >> 5, lo = l & 31;
#pragma unroll
    for (int q = 0; q < 4; ++q) {
        const int row = wid * 8 + q * 2;
        const float* gs = bbase + (size_t)(row + sub) * (2 * N_) + st * RF + lo * 4;
        __builtin_amdgcn_global_load_lds(
            (const __attribute__((address_space(1))) unsigned int*)gs,
            (__attribute__((address_space(3))) unsigned int*)&ldsbuf[row * RF],
            16, 0, 0);
    }
}

__global__ void __launch_bounds__(256, 3)
hib_mfma(const float* __restrict__ batch,
         const int* __restrict__ labels,
         const float* __restrict__ eps1, const float* __restrict__ eps2,
         const unsigned short* __restrict__ wf,
         const float* __restrict__ b1, const float* __restrict__ b2,
         const float* __restrict__ bmu, const float* __restrict__ bv,
         const float* __restrict__ sw, const float* __restrict__ sb,
         float* __restrict__ out)
{
    __shared__ float lds[NBUF][32 * RF];   // 3 x 16KB stage buffers
    __shared__ float sacc[32];

    const int tid = threadIdx.x;
    const int b   = blockIdx.x;
    const int wid = tid >> 6, l = tid & 63;
    const int c   = l & 15, kb = l >> 4;

    if (tid < 32) sacc[tid] = 0.f;

    // weight A-frags, register-resident
    const bf16x8* wfv = (const bf16x8*)wf;
    const bf16x8 A1a = wfv[0 * 64 + l], A1b = wfv[1 * 64 + l];
    const bf16x8 A2a = wfv[2 * 64 + l], A2b = wfv[3 * 64 + l];
    const bf16x8 Ahd = wfv[4 * 64 + l];

    const int r4 = 4 * kb;
    const bool is_v = (kb >= 2);
    const int  z4   = 4 * (kb & 1);
    f32x4 c1a, c1b, c2a, c2b, chd;
    c1a[0] = b1[r4];      c1a[1] = b1[r4 + 1];      c1a[2] = b1[r4 + 2];      c1a[3] = b1[r4 + 3];
    c1b[0] = b1[16 + r4]; c1b[1] = b1[16 + r4 + 1]; c1b[2] = b1[16 + r4 + 2]; c1b[3] = b1[16 + r4 + 3];
    c2a[0] = b2[r4];      c2a[1] = b2[r4 + 1];      c2a[2] = b2[r4 + 2];      c2a[3] = b2[r4 + 3];
    c2b[0] = b2[16 + r4]; c2b[1] = b2[16 + r4 + 1]; c2b[2] = b2[16 + r4 + 2]; c2b[3] = b2[16 + r4 + 3];
    if (is_v) { chd[0] = bv[z4];  chd[1] = bv[z4 + 1];  chd[2] = bv[z4 + 2];  chd[3] = bv[z4 + 3]; }
    else      { chd[0] = bmu[z4]; chd[1] = bmu[z4 + 1]; chd[2] = bmu[z4 + 2]; chd[3] = bmu[z4 + 3]; }

    f32x4 acc0 = {0.f, 0.f, 0.f, 0.f};
    f32x4 acc1 = {0.f, 0.f, 0.f, 0.f};

    const float* bbase = batch + (size_t)b * 32 * (2 * N_);

    // ---- prologue: S(0), S(1) in flight; require S(0) resident ----
    stage_issue(bbase, lds[0], 0, wid, l);
    stage_issue(bbase, lds[1], 1, wid, l);
    asm volatile("s_waitcnt vmcnt(4)" ::: "memory");   // S(0) done (FIFO)
    __builtin_amdgcn_s_barrier();
    __builtin_amdgcn_sched_barrier(0);

#pragma unroll 1
    for (int t = 0; t < NSTG; ++t) {
        const int cur = t % NBUF;
        // prefetch 2 ahead into the buffer last read at stage t-1 (WAR safe:
        // barrier at end of t-1 ordered all reads before this issue)
        if (t + 2 < NSTG)
            stage_issue(bbase, lds[(t + 2) % NBUF], t + 2, wid, l);

        // ---- compute from lds[cur]: this wave's 16 points x 2 channels ----
        float2 xr[8];
#pragma unroll
        for (int j = 0; j < 8; j++)
            xr[j] = *(const float2*)&lds[cur][(kb * 8 + j) * RF + (wid * 16 + c) * 2];

        bf16x8 f0, f1;
#pragma unroll
        for (int j = 0; j < 8; j++) {
            f0[j] = (short)f2bf_u(xr[j].x);
            f1[j] = (short)f2bf_u(xr[j].y);
        }

        f32x4 d1a0 = __builtin_amdgcn_mfma_f32_16x16x32_bf16(A1a, f0, c1a, 0, 0, 0);
        f32x4 d1b0 = __builtin_amdgcn_mfma_f32_16x16x32_bf16(A1b, f0, c1b, 0, 0, 0);
        f32x4 d1a1 = __builtin_amdgcn_mfma_f32_16x16x32_bf16(A1a, f1, c1a, 0, 0, 0);
        f32x4 d1b1 = __builtin_amdgcn_mfma_f32_16x16x32_bf16(A1b, f1, c1b, 0, 0, 0);

        bf16x8 p20 = pack_relu(d1a0, d1b0);
        bf16x8 p21 = pack_relu(d1a1, d1b1);

        f32x4 d2a0 = __builtin_amdgcn_mfma_f32_16x16x32_bf16(A2a, p20, c2a, 0, 0, 0);
        f32x4 d2b0 = __builtin_amdgcn_mfma_f32_16x16x32_bf16(A2b, p20, c2b, 0, 0, 0);
        f32x4 d2a1 = __builtin_amdgcn_mfma_f32_16x16x32_bf16(A2a, p21, c2a, 0, 0, 0);
        f32x4 d2b1 = __builtin_amdgcn_mfma_f32_16x16x32_bf16(A2b, p21, c2b, 0, 0, 0);

        bf16x8 p30 = pack_relu(d2a0, d2b0);
        bf16x8 p31 = pack_relu(d2a1, d2b1);

        f32x4 e0 = __builtin_amdgcn_mfma_f32_16x16x32_bf16(Ahd, p30, chd, 0, 0, 0);
        f32x4 e1 = __builtin_amdgcn_mfma_f32_16x16x32_bf16(Ahd, p31, chd, 0, 0, 0);

        if (!is_v) {
            acc0[0] += e0[0]; acc0[1] += e0[1]; acc0[2] += e0[2]; acc0[3] += e0[3];
            acc1[0] += e1[0]; acc1[1] += e1[1]; acc1[2] += e1[2]; acc1[3] += e1[3];
        } else {
            acc0[0] += rcp_fast(fmaxf(softplus_cheap(e0[0]), VAR_MIN));
            acc0[1] += rcp_fast(fmaxf(softplus_cheap(e0[1]), VAR_MIN));
            acc0[2] += rcp_fast(fmaxf(softplus_cheap(e0[2]), VAR_MIN));
            acc0[3] += rcp_fast(fmaxf(softplus_cheap(e0[3]), VAR_MIN));
            acc1[0] += rcp_fast(fmaxf(softplus_cheap(e1[0]), VAR_MIN));
            acc1[1] += rcp_fast(fmaxf(softplus_cheap(e1[1]), VAR_MIN));
            acc1[2] += rcp_fast(fmaxf(softplus_cheap(e1[2]), VAR_MIN));
            acc1[3] += rcp_fast(fmaxf(softplus_cheap(e1[3]), VAR_MIN));
        }

        // counted wait BEFORE barrier: S(t+1) resident for every wave when
        // any wave proceeds; S(t+2) stays in flight (never drain to 0 mid-loop)
        if (t + 2 < NSTG)
            asm volatile("s_waitcnt vmcnt(4)" ::: "memory");
        else
            asm volatile("s_waitcnt vmcnt(0)" ::: "memory");
        __builtin_amdgcn_s_barrier();
        __builtin_amdgcn_sched_barrier(0);
    }

    // ---- reduce over the 16 point-columns in each lane group ----
    red16(acc0);
    red16(acc1);

    if (c == 0) {
        const int base = (is_v ? 16 : 0) + z4;   // +0: ch0, +8: ch1
        atomicAdd(&sacc[base + 0],     acc0[0]);
        atomicAdd(&sacc[base + 1],     acc0[1]);
        atomicAdd(&sacc[base + 2],     acc0[2]);
        atomicAdd(&sacc[base + 3],     acc0[3]);
        atomicAdd(&sacc[base + 8 + 0], acc1[0]);
        atomicAdd(&sacc[base + 8 + 1], acc1[1]);
        atomicAdd(&sacc[base + 8 + 2], acc1[2]);
        atomicAdd(&sacc[base + 8 + 3], acc1[3]);
    }
    __syncthreads();   // full drain is fine here (nothing async outstanding)

    // ---- per-b tail on wave 0: pooling, KL, S x S sampled loss ----
    if (tid < 64) {
        const float a    = softplus_ref(sw[0]);
        const float sbv_ = sb[0];

        float muA[8], muB[8], sgA[8], sgB[8];
#pragma unroll
        for (int z = 0; z < 8; z++) {
            muA[z] = sacc[z];
            muB[z] = sacc[8 + z];
            sgA[z] = sqrtf(1.0f / sacc[16 + z]);
            sgB[z] = sqrtf(1.0f / sacc[24 + z]);
        }
        const int i = tid >> 3, j = tid & 7;
        float d2 = 0.f;
#pragma unroll
        for (int z = 0; z < 8; z++) {
            float e1 = eps1[((size_t)b * 8 + i) * 8 + z];
            float e2 = eps2[((size_t)b * 8 + j) * 8 + z];
            float zz1 = fmaf(sgA[z], e1, muA[z]);
            float zz2 = fmaf(sgB[z], e2, muB[z]);
            float d = zz1 - zz2;
            d2 = fmaf(d, d, d2);
        }
        const float lab = (float)labels[b];
        float contrib = softplus_ref(a * sqrtf(d2) - sbv_) * lab
                      * (1.0f / (64.0f * (float)B_));

        if (tid < 16) {
            const int cc = tid >> 3, z = tid & 7;
            float iv  = sacc[16 + cc * 8 + z];
            float var = 1.0f / iv;
            float m   = sacc[cc * 8 + z];
            contrib += (-0.5f * logf(var) + 0.5f * (var + m * m) - 0.5f)
                       * (BETA / (8.0f * (float)B_));
        }
#pragma unroll
        for (int off = 32; off; off >>= 1) contrib += __shfl_down(contrib, off);
        if (tid == 0) atomicAdd(out, contrib);
    }
}

extern "C" void kernel_launch(void* const* d_in, const int* in_sizes, int n_in,
                              void* d_out, int out_size, void* d_ws, size_t ws_size,
                              hipStream_t stream)
{
    (void)in_sizes; (void)n_in; (void)out_size; (void)ws_size;
    const float* batch  = (const float*)d_in[0];
    const int*   labels = (const int*)  d_in[1];
    const float* eps1   = (const float*)d_in[2];
    const float* eps2   = (const float*)d_in[3];
    const float* W1     = (const float*)d_in[4];
    const float* b1     = (const float*)d_in[5];
    const float* W2     = (const float*)d_in[6];
    const float* b2     = (const float*)d_in[7];
    const float* Wmu    = (const float*)d_in[8];
    const float* bmu    = (const float*)d_in[9];
    const float* Wv     = (const float*)d_in[10];
    const float* bv     = (const float*)d_in[11];
    const float* sw     = (const float*)d_in[12];
    const float* sb     = (const float*)d_in[13];

    unsigned short* wf = (unsigned short*)d_ws;  // 5 frags x 64 lanes x 8 bf16

    hipMemsetAsync(d_out, 0, sizeof(float), stream);
    hib_prep<<<1, 64, 0, stream>>>(W1, W2, Wmu, Wv, wf);
    hib_mfma<<<B_, 256, 0, stream>>>(batch, labels, eps1, eps2, wf,
                                     b1, b2, bmu, bv, sw, sb, (float*)d_out);
}